// Round 8
// baseline (325.711 us; speedup 1.0000x reference)
//
#include <hip/hip_runtime.h>
#include <hip/hip_bf16.h>

#define TPB 256
#define PREP_BLOCKS 64

typedef __attribute__((ext_vector_type(8))) short short8;
typedef __attribute__((ext_vector_type(4))) float f32x4;

// ---- weight image byte offsets (d_ws; first G_LCOPY bytes mirrored in LDS,
//      W3F streamed from L2) ----
// All MFMA weight fragments use the K-permutation
//   phys_k(s, q, j) = 16*(2*s + (j>>2)) + 4*q + (j&3)
// which makes every layer's B-fragment register-local in the lane that owns
// batch row b (lane&15), since C-layout rows are 16*mt + 4*quad + r.
#define G_W2F   0        // [t=3][s=4][lane=64][j=8] bf16  12288  (A-frags, perm)
#define G_MVF   12288    // [s=4][64][8] bf16               4096  (A-frags, perm)
#define G_D1F   16384    // [t=2][64][8] bf16               2048  (A-frags, perm)
#define G_D2F   18432    // [64][8] bf16                    1024  (A-frags, perm)
#define G_CEAB  19456    // [e=4][n=128][4] bf16 {a0,a1,a2,ce} 4096
#define G_B2P   23552    // [48] f32 (pad 0)
#define G_B3    23744    // [128] f32
#define G_BMV   24256    // [16] f32 (bm|bv)
#define G_D1C   24320    // [32] f32 (Wd1 col0 + bd1)
#define G_BD2   24448    // [16] f32 (pad 0)
#define G_LCOPY 24512    // LDS copy size -> 24576 alloc -> 6 blocks/CU
#define G_W3F   24512    // [nt=8][s=2][64][8] bf16        16384  (L2-streamed)
#define G_END   40896

__device__ __forceinline__ unsigned short f2bf(float f) {
    unsigned int u = __float_as_uint(f);
    unsigned int r = u + 0x7fffu + ((u >> 16) & 1u);   // RNE
    return (unsigned short)(r >> 16);
}
__device__ __forceinline__ unsigned int pk(float a, float b) {
    __hip_bfloat162 h = __float22bfloat162_rn(make_float2(a, b));
    unsigned int u; __builtin_memcpy(&u, &h, 4); return u;
}

__global__ void prep_kernel(
    const float* __restrict__ W1, const float* __restrict__ b1,
    const float* __restrict__ W2, const float* __restrict__ b2,
    const float* __restrict__ W3, const float* __restrict__ b3,
    const float* __restrict__ Wm, const float* __restrict__ bm,
    const float* __restrict__ Wv, const float* __restrict__ bv,
    const float* __restrict__ Wd1, const float* __restrict__ bd1,
    const float* __restrict__ Wd2, const float* __restrict__ bd2,
    unsigned char* __restrict__ ws)
{
    const int g0 = blockIdx.x * TPB + threadIdx.x;
    const int gs = gridDim.x * TPB;
    // W2 as A-fragments of s^T = W2 . x1^T, permuted K
    unsigned short* w2f = (unsigned short*)(ws + G_W2F);
    for (int i = g0; i < 6144; i += gs) {
        int j = i & 7, lane = (i >> 3) & 63, ts = i >> 9;
        int t = ts >> 2, s = ts & 3, q = lane >> 4;
        int n = 16 * t + (lane & 15);
        int phys = 16 * (2 * s + (j >> 2)) + 4 * q + (j & 3);   // 0..127
        w2f[i] = (n < 39) ? f2bf(W2[n * 128 + phys]) : 0;
    }
    // W3 as A-fragments of x3^T = W3 . s^T, permuted K (39 padded to 64)
    unsigned short* w3f = (unsigned short*)(ws + G_W3F);
    for (int i = g0; i < 8192; i += gs) {
        int j = i & 7, lane = (i >> 3) & 63, ns = i >> 9;
        int nt = ns >> 1, s = ns & 1, q = lane >> 4;
        int n = 16 * nt + (lane & 15);
        int phys = 16 * (2 * s + (j >> 2)) + 4 * q + (j & 3);   // 0..63
        w3f[i] = (phys < 39) ? f2bf(W3[n * 39 + phys]) : 0;
    }
    // Wm|Wv as A-fragments, permuted K=128
    unsigned short* mvf = (unsigned short*)(ws + G_MVF);
    for (int i = g0; i < 2048; i += gs) {
        int j = i & 7, lane = (i >> 3) & 63, s = i >> 9;
        int q = lane >> 4, n = lane & 15;
        int phys = 16 * (2 * s + (j >> 2)) + 4 * q + (j & 3);
        mvf[i] = f2bf(n < 8 ? Wm[n * 128 + phys] : Wv[(n - 8) * 128 + phys]);
    }
    // Wd1 (cols 5..24) as A-fragments, permuted K=32 (20 padded)
    unsigned short* d1f = (unsigned short*)(ws + G_D1F);
    for (int i = g0; i < 1024; i += gs) {
        int j = i & 7, lane = (i >> 3) & 63, tt = i >> 9;
        int q = lane >> 4, n = 16 * tt + (lane & 15);
        int phys = 16 * (j >> 2) + 4 * q + (j & 3);             // 0..31
        d1f[i] = (phys < 20) ? f2bf(Wd1[n * 25 + 5 + phys]) : 0;
    }
    // Wd2 as A-fragments, permuted K=32
    unsigned short* d2f = (unsigned short*)(ws + G_D2F);
    for (int i = g0; i < 512; i += gs) {
        int j = i & 7, lane = i >> 3;
        int q = lane >> 4, n = lane & 15;
        int phys = 16 * (j >> 2) + 4 * q + (j & 3);
        d2f[i] = (n < 12) ? f2bf(Wd2[n * 32 + phys]) : 0;
    }
    unsigned short* ceab = (unsigned short*)(ws + G_CEAB);
    for (int i = g0; i < 2048; i += gs) {           // [e][n][4] {a0,a1,a2,ce}
        int c = i & 3, n = (i >> 2) & 127, e = i >> 9;
        float v = (c < 3) ? W1[n * 13 + 10 + c]
                          : (W1[n * 13 + 0] + W1[n * 13 + 6 + e] + b1[n]);
        ceab[i] = f2bf(v);
    }
    float* fb = (float*)(ws + G_B2P);
    for (int i = g0; i < 48; i += gs) fb[i] = (i < 39) ? b2[i] : 0.f;
    fb = (float*)(ws + G_B3);
    for (int i = g0; i < 128; i += gs) fb[i] = b3[i];
    fb = (float*)(ws + G_BMV);
    for (int i = g0; i < 16; i += gs) fb[i] = (i < 8) ? bm[i] : bv[i - 8];
    fb = (float*)(ws + G_D1C);
    for (int i = g0; i < 32; i += gs) fb[i] = Wd1[i * 25 + 0] + bd1[i];
    fb = (float*)(ws + G_BD2);
    for (int i = g0; i < 16; i += gs) fb[i] = (i < 12) ? bd2[i] : 0.f;
}

union S8 { short8 v; uint4 u; };

#define MFMA(a, b, c) __builtin_amdgcn_mfma_f32_16x16x32_bf16(a, b, c, 0, 0, 0)

// r7 body; LDS shrunk to 24512B (no W3F -> 6 blocks/CU) and VGPR capped at 85
// via __launch_bounds__(TPB,6) -> cap 6 waves/SIMD (75%). r7 used 76 regs
// naturally, so no spill expected (spill signature: WRITE_SIZE >> 37 MB).
// W3F (16KB, 16 loads/wave) streams from L2 as in r4.
__global__ __launch_bounds__(TPB, 6) void vae_mfma(
    const float* __restrict__ ic, const float* __restrict__ cc,
    const float* __restrict__ eps,
    const unsigned char* __restrict__ ws,
    float* __restrict__ out, int B)
{
    __shared__ __attribute__((aligned(16))) unsigned char lds[G_LCOPY];
    const int tid = threadIdx.x;

    {   // weight image (sans W3F) -> LDS (linear, coalesced; L2-hot)
        const uint4* src = (const uint4*)ws;
        uint4* dst = (uint4*)lds;
        #pragma unroll
        for (int it = 0; it < 6; it++) {
            int idx = it * TPB + tid;
            if (idx < G_LCOPY / 16) dst[idx] = src[idx];
        }
    }
    __syncthreads();

    const int lane = tid & 63, w = tid >> 6;
    const int quad = lane >> 4, n16 = lane & 15;
    const bool q0 = (quad == 0);
    const long rb = ((long)blockIdx.x * 4 + w) * 16;
    const long Rl = rb + n16;              // this lane's batch row

    // ---- q0 lanes: predicate packs per edge (pre-packed bf16 pairs, 8 u32) ----
    unsigned int bpx[4] = {0,0,0,0}, bpy[4] = {0,0,0,0};
    if (q0) {
        const float* crow = cc + Rl * 30;
        float2 u0 = *(const float2*)(crow);
        float2 u1 = *(const float2*)(crow + 2);
        float2 u2 = *(const float2*)(crow + 10);
        float2 u3 = *(const float2*)(crow + 12);
        bpx[0] = pk(u0.x, u2.x); bpy[0] = pk(crow[14], 1.0f);
        bpx[1] = pk(u0.y, u2.y); bpy[1] = pk(crow[18], 1.0f);
        bpx[2] = pk(u1.x, u3.x); bpy[2] = pk(crow[22], 1.0f);
        bpx[3] = pk(u1.y, u3.y); bpy[3] = pk(crow[26], 1.0f);
    }

    // ---- W2 A-frags resident (from LDS) + per-quad bias vectors ----
    S8 W2F[12];
    #pragma unroll
    for (int ts = 0; ts < 12; ts++)
        W2F[ts].u = *(const uint4*)(lds + G_W2F + (ts * 64 + lane) * 16);
    const float* b2p = (const float*)(lds + G_B2P);
    f32x4 b2q[3];
    #pragma unroll
    for (int t = 0; t < 3; t++)
        b2q[t] = *(const f32x4*)(b2p + 16 * t + 4 * quad);

    f32x4 ss0 = {0,0,0,0}, ss1 = {0,0,0,0}, ss2 = {0,0,0,0};

    // ---- message MLP: L1 (x1^T tiles) -> in-reg pack -> L2 (s^T), per edge ----
    #pragma unroll
    for (int e = 0; e < 4; e++) {
        S8 bp;                                   // B = p-vector (k=0..3 in q0)
        bp.u.x = bpx[e]; bp.u.y = bpy[e]; bp.u.z = 0u; bp.u.w = 0u;
        const unsigned long long* cb =
            (const unsigned long long*)(lds + G_CEAB + e * 1024);
        S8 xf[4];                                // x1^T B-frags for L2 (perm K)
        #pragma unroll
        for (int mt = 0; mt < 8; mt++) {
            unsigned long long bw = cb[mt * 16 + n16];
            S8 af;                               // A = ceab rows (k=0..3 in q0)
            af.u.x = q0 ? (unsigned int)bw : 0u;
            af.u.y = q0 ? (unsigned int)(bw >> 32) : 0u;
            af.u.z = 0u; af.u.w = 0u;
            f32x4 z4 = {0,0,0,0};
            f32x4 cr = MFMA(af.v, bp.v, z4);     // lane: x1[b=n16][16mt+4q+r]
            unsigned int lo = pk(fmaxf(cr[0], 0.f), fmaxf(cr[1], 0.f));
            unsigned int hi = pk(fmaxf(cr[2], 0.f), fmaxf(cr[3], 0.f));
            if ((mt & 1) == 0) { xf[mt >> 1].u.x = lo; xf[mt >> 1].u.y = hi; }
            else               { xf[mt >> 1].u.z = lo; xf[mt >> 1].u.w = hi; }
        }
        f32x4 c0 = b2q[0], c1 = b2q[1], c2 = b2q[2];
        #pragma unroll
        for (int s = 0; s < 4; s++) {
            c0 = MFMA(W2F[s].v,     xf[s].v, c0);
            c1 = MFMA(W2F[4 + s].v, xf[s].v, c1);
            c2 = MFMA(W2F[8 + s].v, xf[s].v, c2);
        }
        #pragma unroll
        for (int r = 0; r < 4; r++) {
            ss0[r] += fmaxf(c0[r], 0.f);
            ss1[r] += fmaxf(c1[r], 0.f);
            ss2[r] += fmaxf(c2[r], 0.f);
        }
    }

    // ---- s^T B-frags (K=64, tiles 3 valid + 1 zero pad) ----
    S8 sf0, sf1;
    sf0.u.x = pk(ss0[0], ss0[1]); sf0.u.y = pk(ss0[2], ss0[3]);
    sf0.u.z = pk(ss1[0], ss1[1]); sf0.u.w = pk(ss1[2], ss1[3]);
    sf1.u.x = pk(ss2[0], ss2[1]); sf1.u.y = pk(ss2[2], ss2[3]);
    sf1.u.z = 0u; sf1.u.w = 0u;   // rows 48..63 pad (rows 39..47 exact zero)

    // ---- L3: x3^T = W3 . s^T (B-frags from L2 global); pack heads B-frags ----
    const uint4* w3g = (const uint4*)(ws + G_W3F);
    const float* b3p = (const float*)(lds + G_B3);
    S8 hf[4];
    #pragma unroll
    for (int nt = 0; nt < 8; nt++) {
        f32x4 c = *(const f32x4*)(b3p + nt * 16 + 4 * quad);
        S8 a0, a1;
        a0.u = w3g[(nt * 2 + 0) * 64 + lane];
        a1.u = w3g[(nt * 2 + 1) * 64 + lane];
        c = MFMA(a0.v, sf0.v, c);
        c = MFMA(a1.v, sf1.v, c);
        unsigned int lo = pk(fmaxf(c[0], 0.f), fmaxf(c[1], 0.f));
        unsigned int hi = pk(fmaxf(c[2], 0.f), fmaxf(c[3], 0.f));
        if ((nt & 1) == 0) { hf[nt >> 1].u.x = lo; hf[nt >> 1].u.y = hi; }
        else               { hf[nt >> 1].u.z = lo; hf[nt >> 1].u.w = hi; }
    }

    // ---- heads: [mn|lv]^T, lane holds rows 4q+r of (mn0..7,lv0..7) ----
    f32x4 cm = *(const f32x4*)((const float*)(lds + G_BMV) + 4 * quad);
    #pragma unroll
    for (int s = 0; s < 4; s++) {
        S8 a; a.u = *(const uint4*)(lds + G_MVF + (s * 64 + lane) * 16);
        cm = MFMA(a.v, hf[s].v, cm);
    }

    // ---- reparameterization: lv lives in q2/q3, pull to q0/q1 ----
    const int addrLv = ((lane + 32) & 63) << 2;
    float lvv[4];
    #pragma unroll
    for (int r = 0; r < 4; r++)
        lvv[r] = __int_as_float(
            __builtin_amdgcn_ds_bpermute(addrLv, __float_as_int(cm[r])));
    float4 ev = *(const float4*)(eps + Rl * 8 + 4 * (quad & 1));
    f32x4 zz;
    zz[0] = fmaf(ev.x, __expf(0.5f * lvv[0]), cm[0]);
    zz[1] = fmaf(ev.y, __expf(0.5f * lvv[1]), cm[1]);
    zz[2] = fmaf(ev.z, __expf(0.5f * lvv[2]), cm[2]);
    zz[3] = fmaf(ev.w, __expf(0.5f * lvv[3]), cm[3]);
    // stores: q0/q1 -> means, q2/q3 -> logvar; q0/q1 -> z
    float* pml = (float*)((quad < 2) ? (out + (long)B * 12) : (out + (long)B * 20));
    *(float4*)(pml + Rl * 8 + 4 * (quad & 1)) = *(float4*)&cm;
    if (quad < 2)
        *(float4*)(out + (long)B * 28 + Rl * 8 + 4 * quad) = *(float4*)&zz;

    // ---- z exchange for decoder: q0 needs z[4..7] (from q1), q3 needs z[0..3] (from q0)
    const int addrZ = (n16 + (q0 ? 16 : 0)) << 2;
    float zr[4];
    #pragma unroll
    for (int r = 0; r < 4; r++)
        zr[r] = __int_as_float(
            __builtin_amdgcn_ds_bpermute(addrZ, __float_as_int(zz[r])));

    // ---- decoder input B-frag: phys = [icO(12) | z(8) | 0-pad] permuted ----
    const float* irow = ic + Rl * 30;
    float d0, d1, d2, d3;
    if (quad == 3)      { d0 = zr[0];    d1 = zr[1];    d2 = zr[2];    d3 = zr[3]; }
    else if (quad == 2) { d0 = irow[14]; d1 = irow[18]; d2 = irow[22]; d3 = irow[26]; }
    else {
        const float* p = irow + (quad ? 10 : 0);
        float2 u0 = *(const float2*)(p);
        float2 u1 = *(const float2*)(p + 2);
        d0 = u0.x; d1 = u0.y; d2 = u1.x; d3 = u1.y;
    }
    S8 df;
    df.u.x = pk(d0, d1);
    df.u.y = pk(d2, d3);
    df.u.z = q0 ? pk(zr[0], zr[1]) : 0u;
    df.u.w = q0 ? pk(zr[2], zr[3]) : 0u;

    // ---- decoder layer 1: h^T (2 tiles) ----
    const float* d1c = (const float*)(lds + G_D1C);
    S8 a;
    f32x4 ct = *(const f32x4*)(d1c + 4 * quad);
    a.u = *(const uint4*)(lds + G_D1F + (0 * 64 + lane) * 16);
    f32x4 h0 = MFMA(a.v, df.v, ct);
    ct = *(const f32x4*)(d1c + 16 + 4 * quad);
    a.u = *(const uint4*)(lds + G_D1F + (1 * 64 + lane) * 16);
    f32x4 h1 = MFMA(a.v, df.v, ct);
    S8 hf2;
    hf2.u.x = pk(fmaxf(h0[0], 0.f), fmaxf(h0[1], 0.f));
    hf2.u.y = pk(fmaxf(h0[2], 0.f), fmaxf(h0[3], 0.f));
    hf2.u.z = pk(fmaxf(h1[0], 0.f), fmaxf(h1[1], 0.f));
    hf2.u.w = pk(fmaxf(h1[2], 0.f), fmaxf(h1[3], 0.f));

    // ---- decoder layer 2 + sigmoid + coalesced float4 recon store ----
    f32x4 c2 = *(const f32x4*)((const float*)(lds + G_BD2) + 4 * quad);
    S8 a2; a2.u = *(const uint4*)(lds + G_D2F + lane * 16);
    c2 = MFMA(a2.v, hf2.v, c2);
    if (quad < 3) {
        float4 o;
        o.x = 1.f / (1.f + __expf(-c2[0]));
        o.y = 1.f / (1.f + __expf(-c2[1]));
        o.z = 1.f / (1.f + __expf(-c2[2]));
        o.w = 1.f / (1.f + __expf(-c2[3]));
        *(float4*)(out + Rl * 12 + 4 * quad) = o;
    }
}

extern "C" void kernel_launch(void* const* d_in, const int* in_sizes, int n_in,
                              void* d_out, int out_size, void* d_ws, size_t ws_size,
                              hipStream_t stream) {
    const float* ic  = (const float*)d_in[0];   // initial_c [B,30]
    const float* cc  = (const float*)d_in[2];   // current_c [B,30]
    const float* eps = (const float*)d_in[3];   // eps [B,8]

    const int B = in_sizes[3] / 8;              // 262144
    const int nblocks = B / 64;                 // 4096

    prep_kernel<<<PREP_BLOCKS, TPB, 0, stream>>>(
        (const float*)d_in[4],  (const float*)d_in[5],
        (const float*)d_in[6],  (const float*)d_in[7],
        (const float*)d_in[8],  (const float*)d_in[9],
        (const float*)d_in[10], (const float*)d_in[11],
        (const float*)d_in[12], (const float*)d_in[13],
        (const float*)d_in[14], (const float*)d_in[15],
        (const float*)d_in[16], (const float*)d_in[17],
        (unsigned char*)d_ws);
    vae_mfma<<<nblocks, TPB, 0, stream>>>(
        ic, cc, eps, (const unsigned char*)d_ws, (float*)d_out, B);
}

// Round 9
// 302.989 us; speedup vs baseline: 1.0750x; 1.0750x over previous
//
#include <hip/hip_runtime.h>
#include <hip/hip_bf16.h>

#define TPB 256
#define PREP_BLOCKS 64
#define NBLK 1024

typedef __attribute__((ext_vector_type(8))) short short8;
typedef __attribute__((ext_vector_type(4))) float f32x4;

// ---- weight image byte offsets (d_ws; whole image mirrored in LDS) ----
// All MFMA weight fragments use the K-permutation
//   phys_k(s, q, j) = 16*(2*s + (j>>2)) + 4*q + (j&3)
// which makes every layer's B-fragment register-local in the lane that owns
// batch row b (lane&15), since C-layout rows are 16*mt + 4*quad + r.
#define G_W2F   0        // [t=3][s=4][lane=64][j=8] bf16  12288  (A-frags, perm)
#define G_MVF   12288    // [s=4][64][8] bf16               4096  (A-frags, perm)
#define G_D1F   16384    // [t=2][64][8] bf16               2048  (A-frags, perm)
#define G_D2F   18432    // [64][8] bf16                    1024  (A-frags, perm)
#define G_CEAB  19456    // [e=4][n=128][4] bf16 {a0,a1,a2,ce} 4096
#define G_B2P   23552    // [48] f32 (pad 0)
#define G_B3    23744    // [128] f32
#define G_BMV   24256    // [16] f32 (bm|bv)
#define G_D1C   24320    // [32] f32 (Wd1 col0 + bd1)
#define G_BD2   24448    // [16] f32 (pad 0)
#define G_W3F   24512    // [nt=8][s=2][64][8] bf16        16384  (A-frags, perm)
#define G_END   40896    // LDS alloc 40960 = exactly 160KiB/4 -> 4 blocks/CU

__device__ __forceinline__ unsigned short f2bf(float f) {
    unsigned int u = __float_as_uint(f);
    unsigned int r = u + 0x7fffu + ((u >> 16) & 1u);   // RNE
    return (unsigned short)(r >> 16);
}
__device__ __forceinline__ unsigned int pk(float a, float b) {
    __hip_bfloat162 h = __float22bfloat162_rn(make_float2(a, b));
    unsigned int u; __builtin_memcpy(&u, &h, 4); return u;
}

__global__ void prep_kernel(
    const float* __restrict__ W1, const float* __restrict__ b1,
    const float* __restrict__ W2, const float* __restrict__ b2,
    const float* __restrict__ W3, const float* __restrict__ b3,
    const float* __restrict__ Wm, const float* __restrict__ bm,
    const float* __restrict__ Wv, const float* __restrict__ bv,
    const float* __restrict__ Wd1, const float* __restrict__ bd1,
    const float* __restrict__ Wd2, const float* __restrict__ bd2,
    unsigned char* __restrict__ ws)
{
    const int g0 = blockIdx.x * TPB + threadIdx.x;
    const int gs = gridDim.x * TPB;
    // W2 as A-fragments of s^T = W2 . x1^T, permuted K
    unsigned short* w2f = (unsigned short*)(ws + G_W2F);
    for (int i = g0; i < 6144; i += gs) {
        int j = i & 7, lane = (i >> 3) & 63, ts = i >> 9;
        int t = ts >> 2, s = ts & 3, q = lane >> 4;
        int n = 16 * t + (lane & 15);
        int phys = 16 * (2 * s + (j >> 2)) + 4 * q + (j & 3);   // 0..127
        w2f[i] = (n < 39) ? f2bf(W2[n * 128 + phys]) : 0;
    }
    // W3 as A-fragments of x3^T = W3 . s^T, permuted K (39 padded to 64)
    unsigned short* w3f = (unsigned short*)(ws + G_W3F);
    for (int i = g0; i < 8192; i += gs) {
        int j = i & 7, lane = (i >> 3) & 63, ns = i >> 9;
        int nt = ns >> 1, s = ns & 1, q = lane >> 4;
        int n = 16 * nt + (lane & 15);
        int phys = 16 * (2 * s + (j >> 2)) + 4 * q + (j & 3);   // 0..63
        w3f[i] = (phys < 39) ? f2bf(W3[n * 39 + phys]) : 0;
    }
    // Wm|Wv as A-fragments, permuted K=128
    unsigned short* mvf = (unsigned short*)(ws + G_MVF);
    for (int i = g0; i < 2048; i += gs) {
        int j = i & 7, lane = (i >> 3) & 63, s = i >> 9;
        int q = lane >> 4, n = lane & 15;
        int phys = 16 * (2 * s + (j >> 2)) + 4 * q + (j & 3);
        mvf[i] = f2bf(n < 8 ? Wm[n * 128 + phys] : Wv[(n - 8) * 128 + phys]);
    }
    // Wd1 (cols 5..24) as A-fragments, permuted K=32 (20 padded)
    unsigned short* d1f = (unsigned short*)(ws + G_D1F);
    for (int i = g0; i < 1024; i += gs) {
        int j = i & 7, lane = (i >> 3) & 63, tt = i >> 9;
        int q = lane >> 4, n = 16 * tt + (lane & 15);
        int phys = 16 * (j >> 2) + 4 * q + (j & 3);             // 0..31
        d1f[i] = (phys < 20) ? f2bf(Wd1[n * 25 + 5 + phys]) : 0;
    }
    // Wd2 as A-fragments, permuted K=32
    unsigned short* d2f = (unsigned short*)(ws + G_D2F);
    for (int i = g0; i < 512; i += gs) {
        int j = i & 7, lane = i >> 3;
        int q = lane >> 4, n = lane & 15;
        int phys = 16 * (j >> 2) + 4 * q + (j & 3);
        d2f[i] = (n < 12) ? f2bf(Wd2[n * 32 + phys]) : 0;
    }
    unsigned short* ceab = (unsigned short*)(ws + G_CEAB);
    for (int i = g0; i < 2048; i += gs) {           // [e][n][4] {a0,a1,a2,ce}
        int c = i & 3, n = (i >> 2) & 127, e = i >> 9;
        float v = (c < 3) ? W1[n * 13 + 10 + c]
                          : (W1[n * 13 + 0] + W1[n * 13 + 6 + e] + b1[n]);
        ceab[i] = f2bf(v);
    }
    float* fb = (float*)(ws + G_B2P);
    for (int i = g0; i < 48; i += gs) fb[i] = (i < 39) ? b2[i] : 0.f;
    fb = (float*)(ws + G_B3);
    for (int i = g0; i < 128; i += gs) fb[i] = b3[i];
    fb = (float*)(ws + G_BMV);
    for (int i = g0; i < 16; i += gs) fb[i] = (i < 8) ? bm[i] : bv[i - 8];
    fb = (float*)(ws + G_D1C);
    for (int i = g0; i < 32; i += gs) fb[i] = Wd1[i * 25 + 0] + bd1[i];
    fb = (float*)(ws + G_BD2);
    for (int i = g0; i < 16; i += gs) fb[i] = (i < 12) ? bd2[i] : 0.f;
}

union S8 { short8 v; uint4 u; };

#define MFMA(a, b, c) __builtin_amdgcn_mfma_f32_16x16x32_bf16(a, b, c, 0, 0, 0)

// r7 body made PERSISTENT: 1024 blocks (exactly 4/CU at 40960B LDS), each
// grid-strides over 4 row-chunks. Staging + the only __syncthreads happen
// ONCE; W2 fragments stay register-resident across chunks; no barrier in the
// loop (LDS is read-only weights). All HBM inputs (cc/eps/ic) are loaded at
// the top of each chunk so their ~900cy latency hides under the MFMA chain
// instead of stalling mid-kernel (eps at reparam, ic at decoder).
__global__ __launch_bounds__(TPB, 2) void vae_mfma(
    const float* __restrict__ ic, const float* __restrict__ cc,
    const float* __restrict__ eps,
    const unsigned char* __restrict__ ws,
    float* __restrict__ out, int B)
{
    __shared__ __attribute__((aligned(16))) unsigned char lds[G_END];
    const int tid = threadIdx.x;

    {   // weight image -> LDS (linear, coalesced; L2-hot), once per block
        const uint4* src = (const uint4*)ws;
        uint4* dst = (uint4*)lds;
        #pragma unroll
        for (int it = 0; it < 10; it++) {
            int idx = it * TPB + tid;
            if (idx < G_END / 16) dst[idx] = src[idx];
        }
    }
    __syncthreads();

    const int lane = tid & 63, w = tid >> 6;
    const int quad = lane >> 4, n16 = lane & 15;
    const bool q0 = (quad == 0);

    // ---- W2 A-frags resident across all chunks + per-quad bias vectors ----
    S8 W2F[12];
    #pragma unroll
    for (int ts = 0; ts < 12; ts++)
        W2F[ts].u = *(const uint4*)(lds + G_W2F + (ts * 64 + lane) * 16);
    const float* b2p = (const float*)(lds + G_B2P);
    f32x4 b2q[3];
    #pragma unroll
    for (int t = 0; t < 3; t++)
        b2q[t] = *(const f32x4*)(b2p + 16 * t + 4 * quad);

    const int addrLv = ((lane + 32) & 63) << 2;
    const int addrZ = (n16 + (q0 ? 16 : 0)) << 2;
    const int ntile = B >> 6;                 // 16-row tiles * 4 waves = 64 rows/block

    for (int bt = blockIdx.x; bt < ntile; bt += NBLK) {
        const long rb = ((long)bt * 4 + w) * 16;
        const long Rl = rb + n16;             // this lane's batch row

        // ---- prefetch ALL inputs for this chunk up front ----
        float4 ev = *(const float4*)(eps + Rl * 8 + 4 * (quad & 1));
        const float* irow = ic + Rl * 30;
        float d0 = 0.f, d1 = 0.f, d2 = 0.f, d3 = 0.f;
        if (quad == 2) { d0 = irow[14]; d1 = irow[18]; d2 = irow[22]; d3 = irow[26]; }
        else if (quad < 2) {
            const float* p = irow + (quad ? 10 : 0);
            float2 u0 = *(const float2*)(p);
            float2 u1 = *(const float2*)(p + 2);
            d0 = u0.x; d1 = u0.y; d2 = u1.x; d3 = u1.y;
        }
        unsigned int bpx[4] = {0,0,0,0}, bpy[4] = {0,0,0,0};
        if (q0) {
            const float* crow = cc + Rl * 30;
            float2 u0 = *(const float2*)(crow);
            float2 u1 = *(const float2*)(crow + 2);
            float2 u2 = *(const float2*)(crow + 10);
            float2 u3 = *(const float2*)(crow + 12);
            bpx[0] = pk(u0.x, u2.x); bpy[0] = pk(crow[14], 1.0f);
            bpx[1] = pk(u0.y, u2.y); bpy[1] = pk(crow[18], 1.0f);
            bpx[2] = pk(u1.x, u3.x); bpy[2] = pk(crow[22], 1.0f);
            bpx[3] = pk(u1.y, u3.y); bpy[3] = pk(crow[26], 1.0f);
        }

        f32x4 ss0 = {0,0,0,0}, ss1 = {0,0,0,0}, ss2 = {0,0,0,0};

        // ---- message MLP: L1 (x1^T tiles) -> in-reg pack -> L2 (s^T) ----
        #pragma unroll
        for (int e = 0; e < 4; e++) {
            S8 bp;                               // B = p-vector (k=0..3 in q0)
            bp.u.x = bpx[e]; bp.u.y = bpy[e]; bp.u.z = 0u; bp.u.w = 0u;
            const unsigned long long* cb =
                (const unsigned long long*)(lds + G_CEAB + e * 1024);
            S8 xf[4];                            // x1^T B-frags for L2 (perm K)
            #pragma unroll
            for (int mt = 0; mt < 8; mt++) {
                unsigned long long bw = cb[mt * 16 + n16];
                S8 af;                           // A = ceab rows (k=0..3 in q0)
                af.u.x = q0 ? (unsigned int)bw : 0u;
                af.u.y = q0 ? (unsigned int)(bw >> 32) : 0u;
                af.u.z = 0u; af.u.w = 0u;
                f32x4 z4 = {0,0,0,0};
                f32x4 cr = MFMA(af.v, bp.v, z4); // lane: x1[b=n16][16mt+4q+r]
                unsigned int lo = pk(fmaxf(cr[0], 0.f), fmaxf(cr[1], 0.f));
                unsigned int hi = pk(fmaxf(cr[2], 0.f), fmaxf(cr[3], 0.f));
                if ((mt & 1) == 0) { xf[mt >> 1].u.x = lo; xf[mt >> 1].u.y = hi; }
                else               { xf[mt >> 1].u.z = lo; xf[mt >> 1].u.w = hi; }
            }
            f32x4 c0 = b2q[0], c1 = b2q[1], c2 = b2q[2];
            #pragma unroll
            for (int s = 0; s < 4; s++) {
                c0 = MFMA(W2F[s].v,     xf[s].v, c0);
                c1 = MFMA(W2F[4 + s].v, xf[s].v, c1);
                c2 = MFMA(W2F[8 + s].v, xf[s].v, c2);
            }
            #pragma unroll
            for (int r = 0; r < 4; r++) {
                ss0[r] += fmaxf(c0[r], 0.f);
                ss1[r] += fmaxf(c1[r], 0.f);
                ss2[r] += fmaxf(c2[r], 0.f);
            }
        }

        // ---- s^T B-frags (K=64, tiles 3 valid + 1 zero pad) ----
        S8 sf0, sf1;
        sf0.u.x = pk(ss0[0], ss0[1]); sf0.u.y = pk(ss0[2], ss0[3]);
        sf0.u.z = pk(ss1[0], ss1[1]); sf0.u.w = pk(ss1[2], ss1[3]);
        sf1.u.x = pk(ss2[0], ss2[1]); sf1.u.y = pk(ss2[2], ss2[3]);
        sf1.u.z = 0u; sf1.u.w = 0u;   // rows 48..63 pad (39..47 exact zero)

        // ---- L3: x3^T = W3 . s^T ; pack heads B-frags on the fly ----
        const uint4* w3l = (const uint4*)(lds + G_W3F);
        const float* b3p = (const float*)(lds + G_B3);
        S8 hf[4];
        #pragma unroll
        for (int nt = 0; nt < 8; nt++) {
            f32x4 c = *(const f32x4*)(b3p + nt * 16 + 4 * quad);
            S8 a0, a1;
            a0.u = w3l[(nt * 2 + 0) * 64 + lane];
            a1.u = w3l[(nt * 2 + 1) * 64 + lane];
            c = MFMA(a0.v, sf0.v, c);
            c = MFMA(a1.v, sf1.v, c);
            unsigned int lo = pk(fmaxf(c[0], 0.f), fmaxf(c[1], 0.f));
            unsigned int hi = pk(fmaxf(c[2], 0.f), fmaxf(c[3], 0.f));
            if ((nt & 1) == 0) { hf[nt >> 1].u.x = lo; hf[nt >> 1].u.y = hi; }
            else               { hf[nt >> 1].u.z = lo; hf[nt >> 1].u.w = hi; }
        }

        // ---- heads: [mn|lv]^T, lane holds rows 4q+r of (mn0..7,lv0..7) ----
        f32x4 cm = *(const f32x4*)((const float*)(lds + G_BMV) + 4 * quad);
        #pragma unroll
        for (int s = 0; s < 4; s++) {
            S8 a; a.u = *(const uint4*)(lds + G_MVF + (s * 64 + lane) * 16);
            cm = MFMA(a.v, hf[s].v, cm);
        }

        // ---- reparameterization: lv lives in q2/q3, pull to q0/q1 ----
        float lvv[4];
        #pragma unroll
        for (int r = 0; r < 4; r++)
            lvv[r] = __int_as_float(
                __builtin_amdgcn_ds_bpermute(addrLv, __float_as_int(cm[r])));
        f32x4 zz;
        zz[0] = fmaf(ev.x, __expf(0.5f * lvv[0]), cm[0]);
        zz[1] = fmaf(ev.y, __expf(0.5f * lvv[1]), cm[1]);
        zz[2] = fmaf(ev.z, __expf(0.5f * lvv[2]), cm[2]);
        zz[3] = fmaf(ev.w, __expf(0.5f * lvv[3]), cm[3]);
        // stores: q0/q1 -> means, q2/q3 -> logvar; q0/q1 -> z
        float* pml = (float*)((quad < 2) ? (out + (long)B * 12)
                                         : (out + (long)B * 20));
        *(float4*)(pml + Rl * 8 + 4 * (quad & 1)) = *(float4*)&cm;
        if (quad < 2)
            *(float4*)(out + (long)B * 28 + Rl * 8 + 4 * quad) = *(float4*)&zz;

        // ---- z exchange: q0 needs z[4..7] (from q1), q3 needs z[0..3] ----
        float zr[4];
        #pragma unroll
        for (int r = 0; r < 4; r++)
            zr[r] = __int_as_float(
                __builtin_amdgcn_ds_bpermute(addrZ, __float_as_int(zz[r])));

        // ---- decoder input B-frag: [icO(12) | z(8) | 0-pad] permuted ----
        if (quad == 3) { d0 = zr[0]; d1 = zr[1]; d2 = zr[2]; d3 = zr[3]; }
        S8 df;
        df.u.x = pk(d0, d1);
        df.u.y = pk(d2, d3);
        df.u.z = q0 ? pk(zr[0], zr[1]) : 0u;
        df.u.w = q0 ? pk(zr[2], zr[3]) : 0u;

        // ---- decoder layer 1: h^T (2 tiles) ----
        const float* d1c = (const float*)(lds + G_D1C);
        S8 a;
        f32x4 ct = *(const f32x4*)(d1c + 4 * quad);
        a.u = *(const uint4*)(lds + G_D1F + (0 * 64 + lane) * 16);
        f32x4 h0 = MFMA(a.v, df.v, ct);
        ct = *(const f32x4*)(d1c + 16 + 4 * quad);
        a.u = *(const uint4*)(lds + G_D1F + (1 * 64 + lane) * 16);
        f32x4 h1 = MFMA(a.v, df.v, ct);
        S8 hf2;
        hf2.u.x = pk(fmaxf(h0[0], 0.f), fmaxf(h0[1], 0.f));
        hf2.u.y = pk(fmaxf(h0[2], 0.f), fmaxf(h0[3], 0.f));
        hf2.u.z = pk(fmaxf(h1[0], 0.f), fmaxf(h1[1], 0.f));
        hf2.u.w = pk(fmaxf(h1[2], 0.f), fmaxf(h1[3], 0.f));

        // ---- decoder layer 2 + sigmoid + coalesced float4 recon store ----
        f32x4 c2 = *(const f32x4*)((const float*)(lds + G_BD2) + 4 * quad);
        S8 a2; a2.u = *(const uint4*)(lds + G_D2F + lane * 16);
        c2 = MFMA(a2.v, hf2.v, c2);
        if (quad < 3) {
            float4 o;
            o.x = 1.f / (1.f + __expf(-c2[0]));
            o.y = 1.f / (1.f + __expf(-c2[1]));
            o.z = 1.f / (1.f + __expf(-c2[2]));
            o.w = 1.f / (1.f + __expf(-c2[3]));
            *(float4*)(out + Rl * 12 + 4 * quad) = o;
        }
    }
}

extern "C" void kernel_launch(void* const* d_in, const int* in_sizes, int n_in,
                              void* d_out, int out_size, void* d_ws, size_t ws_size,
                              hipStream_t stream) {
    const float* ic  = (const float*)d_in[0];   // initial_c [B,30]
    const float* cc  = (const float*)d_in[2];   // current_c [B,30]
    const float* eps = (const float*)d_in[3];   // eps [B,8]

    const int B = in_sizes[3] / 8;              // 262144

    prep_kernel<<<PREP_BLOCKS, TPB, 0, stream>>>(
        (const float*)d_in[4],  (const float*)d_in[5],
        (const float*)d_in[6],  (const float*)d_in[7],
        (const float*)d_in[8],  (const float*)d_in[9],
        (const float*)d_in[10], (const float*)d_in[11],
        (const float*)d_in[12], (const float*)d_in[13],
        (const float*)d_in[14], (const float*)d_in[15],
        (const float*)d_in[16], (const float*)d_in[17],
        (unsigned char*)d_ws);
    vae_mfma<<<NBLK, TPB, 0, stream>>>(
        ic, cc, eps, (const unsigned char*)d_ws, (float*)d_out, B);
}

// Round 10
// 181.773 us; speedup vs baseline: 1.7919x; 1.6669x over previous
//
#include <hip/hip_runtime.h>
#include <hip/hip_bf16.h>

#define TPB 256
#define PREP_BLOCKS 64

typedef __attribute__((ext_vector_type(8))) short short8;
typedef __attribute__((ext_vector_type(4))) float f32x4;

// ---- weight image byte offsets (d_ws; whole image mirrored in LDS) ----
// MFMA A-frag HW slot map (16x16x32): lane(q,n16) holds A[n16][k] for
//   k = 16*(j>>2) + 4*q + (j&3),  j=0..7.
// General layers use phys_k(s,q,j) = 16*(2*s + (j>>2)) + 4*q + (j&3) so the
// producer C-layout (row = 4q+r) matches the consumer B-frag register-local.
// L1 uses the 4-quad j0 distribution: k=4q slots carry {a0,a1,a2,ce}.
// Decoder D1F per-quad feature map: q0 j0..7 -> icO[0..7]; q1 j0..3 ->
// icO[8..11]; q2 j0..3 -> z[0..3]; q3 j0..3 -> z[4..7]; rest zero-padded,
// so each quad supplies exactly the z values it computes (no exchange).
#define G_W2F   0        // [t=3][s=4][lane=64][j=8] bf16  12288  (A-frags, perm)
#define G_MVF   12288    // [s=4][64][8] bf16               4096  (A-frags, perm)
#define G_D1F   16384    // [t=2][64][8] bf16               2048  (A-frags, per-quad map)
#define G_D2F   18432    // [64][8] bf16                    1024  (A-frags, perm)
#define G_CEAB  19456    // [e=4][mt=8][lane=64] ushort     4096  (L1 j0-coeffs)
#define G_B2P   23552    // [48] f32 (pad 0)
#define G_B3    23744    // [128] f32
#define G_BMV   24256    // [16] f32 (bm|bv)
#define G_D1C   24320    // [32] f32 (Wd1 col0 + bd1)
#define G_BD2   24448    // [16] f32 (pad 0)
#define G_W3F   24512    // [nt=8][s=2][64][8] bf16        16384  (A-frags, perm)
#define G_END   40896    // LDS alloc 40960 = exactly 160KiB/4 -> 4 blocks/CU

__device__ __forceinline__ unsigned short f2bf(float f) {
    unsigned int u = __float_as_uint(f);
    unsigned int r = u + 0x7fffu + ((u >> 16) & 1u);   // RNE
    return (unsigned short)(r >> 16);
}
__device__ __forceinline__ unsigned int pk(float a, float b) {
    __hip_bfloat162 h = __float22bfloat162_rn(make_float2(a, b));
    unsigned int u; __builtin_memcpy(&u, &h, 4); return u;
}
__device__ __forceinline__ unsigned short bfbits(float v) {
    return (unsigned short)(pk(v, v) & 0xffffu);
}

__global__ void prep_kernel(
    const float* __restrict__ W1, const float* __restrict__ b1,
    const float* __restrict__ W2, const float* __restrict__ b2,
    const float* __restrict__ W3, const float* __restrict__ b3,
    const float* __restrict__ Wm, const float* __restrict__ bm,
    const float* __restrict__ Wv, const float* __restrict__ bv,
    const float* __restrict__ Wd1, const float* __restrict__ bd1,
    const float* __restrict__ Wd2, const float* __restrict__ bd2,
    unsigned char* __restrict__ ws)
{
    const int g0 = blockIdx.x * TPB + threadIdx.x;
    const int gs = gridDim.x * TPB;
    // W2 as A-fragments of s^T = W2 . x1^T, permuted K
    unsigned short* w2f = (unsigned short*)(ws + G_W2F);
    for (int i = g0; i < 6144; i += gs) {
        int j = i & 7, lane = (i >> 3) & 63, ts = i >> 9;
        int t = ts >> 2, s = ts & 3, q = lane >> 4;
        int n = 16 * t + (lane & 15);
        int phys = 16 * (2 * s + (j >> 2)) + 4 * q + (j & 3);   // 0..127
        w2f[i] = (n < 39) ? f2bf(W2[n * 128 + phys]) : 0;
    }
    // W3 as A-fragments of x3^T = W3 . s^T, permuted K (39 padded to 64)
    unsigned short* w3f = (unsigned short*)(ws + G_W3F);
    for (int i = g0; i < 8192; i += gs) {
        int j = i & 7, lane = (i >> 3) & 63, ns = i >> 9;
        int nt = ns >> 1, s = ns & 1, q = lane >> 4;
        int n = 16 * nt + (lane & 15);
        int phys = 16 * (2 * s + (j >> 2)) + 4 * q + (j & 3);   // 0..63
        w3f[i] = (phys < 39) ? f2bf(W3[n * 39 + phys]) : 0;
    }
    // Wm|Wv as A-fragments, permuted K=128
    unsigned short* mvf = (unsigned short*)(ws + G_MVF);
    for (int i = g0; i < 2048; i += gs) {
        int j = i & 7, lane = (i >> 3) & 63, s = i >> 9;
        int q = lane >> 4, n = lane & 15;
        int phys = 16 * (2 * s + (j >> 2)) + 4 * q + (j & 3);
        mvf[i] = f2bf(n < 8 ? Wm[n * 128 + phys] : Wv[(n - 8) * 128 + phys]);
    }
    // Wd1 as A-fragments, per-quad feature map (see header comment)
    unsigned short* d1f = (unsigned short*)(ws + G_D1F);
    for (int i = g0; i < 1024; i += gs) {
        int j = i & 7, lane = (i >> 3) & 63, tt = i >> 9;
        int q = lane >> 4, n = 16 * tt + (lane & 15);
        float v = 0.f;
        if (q == 0)      v = Wd1[n * 25 + 5 + j];            // icO[0..7]
        else if (j < 4)  v = Wd1[n * 25 + 13 + 4 * (q - 1) + j];
        // q1 j0..3 -> cols 13..16 (icO[8..11]); q2 -> 17..20 (z0..3);
        // q3 -> 21..24 (z4..7); all j>=4 (q>0) zero.
        d1f[i] = (q == 0 || j < 4) ? f2bf(v) : 0;
    }
    // Wd2 as A-fragments, permuted K=32
    unsigned short* d2f = (unsigned short*)(ws + G_D2F);
    for (int i = g0; i < 512; i += gs) {
        int j = i & 7, lane = i >> 3;
        int q = lane >> 4, n = lane & 15;
        int phys = 16 * (j >> 2) + 4 * q + (j & 3);
        d2f[i] = (n < 12) ? f2bf(Wd2[n * 32 + phys]) : 0;
    }
    // L1 coefficient image: [e][mt][lane] ushort, j0 slot of quad q:
    //   q0 -> a0 = W1[n][10], q1 -> a1 = W1[n][11], q2 -> a2 = W1[n][12],
    //   q3 -> ce = W1[n][0] + W1[n][6+e] + b1[n]
    unsigned short* ceab = (unsigned short*)(ws + G_CEAB);
    for (int i = g0; i < 2048; i += gs) {
        int lane = i & 63, mt = (i >> 6) & 7, e = i >> 9;
        int q = lane >> 4, n = 16 * mt + (lane & 15);
        float v = (q == 0) ? W1[n * 13 + 10]
                : (q == 1) ? W1[n * 13 + 11]
                : (q == 2) ? W1[n * 13 + 12]
                           : (W1[n * 13 + 0] + W1[n * 13 + 6 + e] + b1[n]);
        ceab[i] = f2bf(v);
    }
    float* fb = (float*)(ws + G_B2P);
    for (int i = g0; i < 48; i += gs) fb[i] = (i < 39) ? b2[i] : 0.f;
    fb = (float*)(ws + G_B3);
    for (int i = g0; i < 128; i += gs) fb[i] = b3[i];
    fb = (float*)(ws + G_BMV);
    for (int i = g0; i < 16; i += gs) fb[i] = (i < 8) ? bm[i] : bv[i - 8];
    fb = (float*)(ws + G_D1C);
    for (int i = g0; i < 32; i += gs) fb[i] = Wd1[i * 25 + 0] + bd1[i];
    fb = (float*)(ws + G_BD2);
    for (int i = g0; i < 16; i += gs) fb[i] = (i < 12) ? bd2[i] : 0.f;
}

union S8 { short8 v; uint4 u; };

#define MFMA(a, b, c) __builtin_amdgcn_mfma_f32_16x16x32_bf16(a, b, c, 0, 0, 0)

// r7 base (68us best) with two targeted chain cuts:
// 1) L1 4-quad j0 K-distribution: A-frag = 1 ds_read_u16 (zero-extended),
//    B-frag = 1 reg move; removes 64 v_cndmask + q0 predicate packing.
// 2) Swapped-heads cm2 (same MVF LDS read at lane (n16+8)&15): every lane
//    owns its (mn,lv) pair and its decoder-z slots -> all 8 ds_bpermute
//    (2 serial ~120cy LDS round-trips) removed, +8 parallel MFMA.
__global__ __launch_bounds__(TPB, 2) void vae_mfma(
    const float* __restrict__ ic, const float* __restrict__ cc,
    const float* __restrict__ eps,
    const unsigned char* __restrict__ ws,
    float* __restrict__ out, int B)
{
    __shared__ __attribute__((aligned(16))) unsigned char lds[G_END];
    const int tid = threadIdx.x;

    {   // weight image -> LDS (linear, coalesced; L2-hot)
        const uint4* src = (const uint4*)ws;
        uint4* dst = (uint4*)lds;
        #pragma unroll
        for (int it = 0; it < 10; it++) {
            int idx = it * TPB + tid;
            if (idx < G_END / 16) dst[idx] = src[idx];
        }
    }
    __syncthreads();

    const int lane = tid & 63, w = tid >> 6;
    const int quad = lane >> 4, n16 = lane & 15;
    const long rb = ((long)blockIdx.x * 4 + w) * 16;
    const long Rl = rb + n16;              // this lane's batch row

    // ---- per-quad predicate values (k=4q slot), packed bf16 low-half ----
    unsigned int bpv[4];
    {
        const float* crow = cc + Rl * 30;
        float pv0, pv1, pv2, pv3;
        if (quad == 0) {                    // pa: cols 0..3
            float2 t0 = *(const float2*)(crow);
            float2 t1 = *(const float2*)(crow + 2);
            pv0 = t0.x; pv1 = t0.y; pv2 = t1.x; pv3 = t1.y;
        } else if (quad == 1) {             // pb: cols 10..13
            float2 t0 = *(const float2*)(crow + 10);
            float2 t1 = *(const float2*)(crow + 12);
            pv0 = t0.x; pv1 = t0.y; pv2 = t1.x; pv3 = t1.y;
        } else if (quad == 2) {             // pc: cols 14,18,22,26
            pv0 = crow[14]; pv1 = crow[18]; pv2 = crow[22]; pv3 = crow[26];
        } else {                            // bias lane: 1.0
            pv0 = pv1 = pv2 = pv3 = 1.0f;
        }
        bpv[0] = (unsigned int)bfbits(pv0);
        bpv[1] = (unsigned int)bfbits(pv1);
        bpv[2] = (unsigned int)bfbits(pv2);
        bpv[3] = (unsigned int)bfbits(pv3);
    }

    // ---- W2 A-frags resident (from LDS) + per-quad bias vectors ----
    S8 W2F[12];
    #pragma unroll
    for (int ts = 0; ts < 12; ts++)
        W2F[ts].u = *(const uint4*)(lds + G_W2F + (ts * 64 + lane) * 16);
    const float* b2p = (const float*)(lds + G_B2P);
    f32x4 b2q[3];
    #pragma unroll
    for (int t = 0; t < 3; t++)
        b2q[t] = *(const f32x4*)(b2p + 16 * t + 4 * quad);

    f32x4 ss0 = {0,0,0,0}, ss1 = {0,0,0,0}, ss2 = {0,0,0,0};

    // ---- message MLP: L1 (x1^T tiles) -> in-reg pack -> L2 (s^T) ----
    #pragma unroll
    for (int e = 0; e < 4; e++) {
        S8 bp;                              // B: k=4q slot = this quad's p-value
        bp.u.x = bpv[e]; bp.u.y = 0u; bp.u.z = 0u; bp.u.w = 0u;
        const unsigned short* cb2 =
            (const unsigned short*)(lds + G_CEAB + e * 1024);
        S8 xf[4];                           // x1^T B-frags for L2 (perm K)
        #pragma unroll
        for (int mt = 0; mt < 8; mt++) {
            S8 af;                          // A: k=4q slot = coeff type q
            af.u.x = (unsigned int)cb2[mt * 64 + lane];
            af.u.y = 0u; af.u.z = 0u; af.u.w = 0u;
            f32x4 z4 = {0,0,0,0};
            f32x4 cr = MFMA(af.v, bp.v, z4);   // lane: x1[b=n16][16mt+4q+r]
            unsigned int lo = pk(fmaxf(cr[0], 0.f), fmaxf(cr[1], 0.f));
            unsigned int hi = pk(fmaxf(cr[2], 0.f), fmaxf(cr[3], 0.f));
            if ((mt & 1) == 0) { xf[mt >> 1].u.x = lo; xf[mt >> 1].u.y = hi; }
            else               { xf[mt >> 1].u.z = lo; xf[mt >> 1].u.w = hi; }
        }
        f32x4 c0 = b2q[0], c1 = b2q[1], c2 = b2q[2];
        #pragma unroll
        for (int s = 0; s < 4; s++) {
            c0 = MFMA(W2F[s].v,     xf[s].v, c0);
            c1 = MFMA(W2F[4 + s].v, xf[s].v, c1);
            c2 = MFMA(W2F[8 + s].v, xf[s].v, c2);
        }
        #pragma unroll
        for (int r = 0; r < 4; r++) {
            ss0[r] += fmaxf(c0[r], 0.f);
            ss1[r] += fmaxf(c1[r], 0.f);
            ss2[r] += fmaxf(c2[r], 0.f);
        }
    }

    // ---- s^T B-frags (K=64, tiles 3 valid + 1 zero pad) ----
    S8 sf0, sf1;
    sf0.u.x = pk(ss0[0], ss0[1]); sf0.u.y = pk(ss0[2], ss0[3]);
    sf0.u.z = pk(ss1[0], ss1[1]); sf0.u.w = pk(ss1[2], ss1[3]);
    sf1.u.x = pk(ss2[0], ss2[1]); sf1.u.y = pk(ss2[2], ss2[3]);
    sf1.u.z = 0u; sf1.u.w = 0u;   // rows 48..63 pad (rows 39..47 exact zero)

    // ---- L3: x3^T = W3 . s^T ; pack heads B-frags on the fly ----
    const uint4* w3l = (const uint4*)(lds + G_W3F);
    const float* b3p = (const float*)(lds + G_B3);
    S8 hf[4];
    #pragma unroll
    for (int nt = 0; nt < 8; nt++) {
        f32x4 c = *(const f32x4*)(b3p + nt * 16 + 4 * quad);
        S8 a0, a1;
        a0.u = w3l[(nt * 2 + 0) * 64 + lane];
        a1.u = w3l[(nt * 2 + 1) * 64 + lane];
        c = MFMA(a0.v, sf0.v, c);
        c = MFMA(a1.v, sf1.v, c);
        unsigned int lo = pk(fmaxf(c[0], 0.f), fmaxf(c[1], 0.f));
        unsigned int hi = pk(fmaxf(c[2], 0.f), fmaxf(c[3], 0.f));
        if ((nt & 1) == 0) { hf[nt >> 1].u.x = lo; hf[nt >> 1].u.y = hi; }
        else               { hf[nt >> 1].u.z = lo; hf[nt >> 1].u.w = hi; }
    }

    // ---- heads: cm = [mn|lv]^T rows 4q+r; cm2 = same weights half-rotated
    //      (rows (4q+r+8)&15) so each lane owns its (mn,lv) pair ----
    f32x4 cm  = *(const f32x4*)((const float*)(lds + G_BMV) + 4 * quad);
    f32x4 cm2 = *(const f32x4*)((const float*)(lds + G_BMV) + 4 * ((quad + 2) & 3));
    const int laneSw = quad * 16 + ((n16 + 8) & 15);
    #pragma unroll
    for (int s = 0; s < 4; s++) {
        S8 a, a2;
        a.u  = *(const uint4*)(lds + G_MVF + (s * 64 + lane) * 16);
        a2.u = *(const uint4*)(lds + G_MVF + (s * 64 + laneSw) * 16);
        cm  = MFMA(a.v,  hf[s].v, cm);
        cm2 = MFMA(a2.v, hf[s].v, cm2);
    }

    // ---- reparameterization, fully lane-local ----
    float4 ev = *(const float4*)(eps + Rl * 8 + 4 * (quad & 1));
    f32x4 zz;
    {
        const bool lo2 = (quad < 2);
        float mn0 = lo2 ? cm[0] : cm2[0], lv0 = lo2 ? cm2[0] : cm[0];
        float mn1 = lo2 ? cm[1] : cm2[1], lv1 = lo2 ? cm2[1] : cm[1];
        float mn2 = lo2 ? cm[2] : cm2[2], lv2 = lo2 ? cm2[2] : cm[2];
        float mn3 = lo2 ? cm[3] : cm2[3], lv3 = lo2 ? cm2[3] : cm[3];
        zz[0] = fmaf(ev.x, __expf(0.5f * lv0), mn0);
        zz[1] = fmaf(ev.y, __expf(0.5f * lv1), mn1);
        zz[2] = fmaf(ev.z, __expf(0.5f * lv2), mn2);
        zz[3] = fmaf(ev.w, __expf(0.5f * lv3), mn3);
    }
    // stores: q0/q1 -> means (cm = mn rows), q2/q3 -> logvar (cm = lv rows)
    float* pml = (float*)((quad < 2) ? (out + (long)B * 12) : (out + (long)B * 20));
    *(float4*)(pml + Rl * 8 + 4 * (quad & 1)) = *(float4*)&cm;
    if (quad < 2)
        *(float4*)(out + (long)B * 28 + Rl * 8 + 4 * quad) = *(float4*)&zz;

    // ---- decoder input B-frag, per-quad feature map (no exchange) ----
    S8 df;
    if (quad == 0) {                        // icO[0..7] = ic cols 0..3,10..13
        const float* irow = ic + Rl * 30;
        float2 a0 = *(const float2*)(irow);
        float2 a1 = *(const float2*)(irow + 2);
        float2 a2 = *(const float2*)(irow + 10);
        float2 a3 = *(const float2*)(irow + 12);
        df.u.x = pk(a0.x, a0.y); df.u.y = pk(a1.x, a1.y);
        df.u.z = pk(a2.x, a2.y); df.u.w = pk(a3.x, a3.y);
    } else if (quad == 1) {                 // icO[8..11] = ic cols 14,18,22,26
        const float* irow = ic + Rl * 30;
        df.u.x = pk(irow[14], irow[18]);
        df.u.y = pk(irow[22], irow[26]);
        df.u.z = 0u; df.u.w = 0u;
    } else {                                // q2: z[0..3], q3: z[4..7] (local)
        df.u.x = pk(zz[0], zz[1]);
        df.u.y = pk(zz[2], zz[3]);
        df.u.z = 0u; df.u.w = 0u;
    }

    // ---- decoder layer 1: h^T (2 tiles) ----
    const float* d1c = (const float*)(lds + G_D1C);
    S8 a;
    f32x4 ct = *(const f32x4*)(d1c + 4 * quad);
    a.u = *(const uint4*)(lds + G_D1F + (0 * 64 + lane) * 16);
    f32x4 h0 = MFMA(a.v, df.v, ct);
    ct = *(const f32x4*)(d1c + 16 + 4 * quad);
    a.u = *(const uint4*)(lds + G_D1F + (1 * 64 + lane) * 16);
    f32x4 h1 = MFMA(a.v, df.v, ct);
    S8 hf2;
    hf2.u.x = pk(fmaxf(h0[0], 0.f), fmaxf(h0[1], 0.f));
    hf2.u.y = pk(fmaxf(h0[2], 0.f), fmaxf(h0[3], 0.f));
    hf2.u.z = pk(fmaxf(h1[0], 0.f), fmaxf(h1[1], 0.f));
    hf2.u.w = pk(fmaxf(h1[2], 0.f), fmaxf(h1[3], 0.f));

    // ---- decoder layer 2 + sigmoid + coalesced float4 recon store ----
    f32x4 c2 = *(const f32x4*)((const float*)(lds + G_BD2) + 4 * quad);
    S8 a2; a2.u = *(const uint4*)(lds + G_D2F + lane * 16);
    c2 = MFMA(a2.v, hf2.v, c2);
    if (quad < 3) {
        float4 o;
        o.x = 1.f / (1.f + __expf(-c2[0]));
        o.y = 1.f / (1.f + __expf(-c2[1]));
        o.z = 1.f / (1.f + __expf(-c2[2]));
        o.w = 1.f / (1.f + __expf(-c2[3]));
        *(float4*)(out + Rl * 12 + 4 * quad) = o;
    }
}

extern "C" void kernel_launch(void* const* d_in, const int* in_sizes, int n_in,
                              void* d_out, int out_size, void* d_ws, size_t ws_size,
                              hipStream_t stream) {
    const float* ic  = (const float*)d_in[0];   // initial_c [B,30]
    const float* cc  = (const float*)d_in[2];   // current_c [B,30]
    const float* eps = (const float*)d_in[3];   // eps [B,8]

    const int B = in_sizes[3] / 8;              // 262144
    const int nblocks = B / 64;                 // 4096

    prep_kernel<<<PREP_BLOCKS, TPB, 0, stream>>>(
        (const float*)d_in[4],  (const float*)d_in[5],
        (const float*)d_in[6],  (const float*)d_in[7],
        (const float*)d_in[8],  (const float*)d_in[9],
        (const float*)d_in[10], (const float*)d_in[11],
        (const float*)d_in[12], (const float*)d_in[13],
        (const float*)d_in[14], (const float*)d_in[15],
        (const float*)d_in[16], (const float*)d_in[17],
        (unsigned char*)d_ws);
    vae_mfma<<<nblocks, TPB, 0, stream>>>(
        ic, cc, eps, (const unsigned char*)d_ws, (float*)d_out, B);
}